// Round 1
// baseline (96.698 us; speedup 1.0000x reference)
//
#include <hip/hip_runtime.h>
#include <math.h>

static constexpr int TLEN  = 1024;  // signal length
static constexpr int NSAMP = 1022;  // N = T - M, M = 2
static constexpr int NSIG  = 128;   // 64 pred + 64 targ
static constexpr int NB    = 10;    // blocks per signal (40 wave-tasks / 4)
static constexpr int SXPAD = 1368;  // sx + sentinel pad (max read idx ~1343)
static constexpr float RTHR = 0.2f;
static constexpr float EPSN = 1e-8f;
static constexpr unsigned TOTAL_BLOCKS = (unsigned)(NB * NSIG);  // 1280

// Last-block detector. Lives in module .data (NOT the poisoned workspace), and
// the single last block re-arms it to 0 before doing the final reduction, so
// every graph replay starts from 0 without an extra memset dispatch.
__device__ unsigned g_done = 0;

__device__ __forceinline__ float wave_sum_f(float v) {
#pragma unroll
  for (int off = 32; off > 0; off >>= 1) v += __shfl_down(v, off);
  return v;
}
__device__ __forceinline__ unsigned wave_sum_u(unsigned v) {
#pragma unroll
  for (int off = 32; off > 0; off >>= 1) v += __shfl_down(v, off);
  return v;
}

// push boolean (|df| <= R) into per-lane 32-bit shift register: mask = 2*mask + b
__device__ __forceinline__ void push_bool(unsigned& mask, float df, float rthr) {
  asm("v_cmp_le_f32 vcc, |%1|, %2\n\t"
      "v_addc_co_u32 %0, vcc, %0, %0, vcc"
      : "+v"(mask)
      : "v"(df), "s"(rthr)
      : "vcc");
}

// One wave-task: lane l owns diagonal d (all lanes share d mod 4 -> OFF is
// wave-uniform and compile-time). Booleans b[k]=|x[k]-x[k+d]|<=R accumulate
// bit-serially (2 VALU); y comes from a rolling 5xfloat4 aligned window:
// exactly one ds_read_b128 per 4 booleans. Epilogue every 16 counts pair/
// triple starts via popcount (identical logic to round 4, absmax 0.0).
template <int OFF>
__device__ __forceinline__ void run_task(const float* sx, const float4* sx4,
                                         int i0, int n, int d, int l,
                                         unsigned& cm2, unsigned& cm3) {
  unsigned mask = 0;
  push_bool(mask, sx[i0] - sx[i0 + d], RTHR);
  push_bool(mask, sx[i0 + 1] - sx[i0 + 1 + d], RTHR);

  int B = (i0 + 2 + d) >> 2;  // float4 index; 4B + OFF == first y index
  float4 c0;
  if (OFF != 0) c0 = sx4[B];  // carried low window reg

  const int nblk = (n + 63) >> 6;
  for (int blk = 0; blk < nblk; ++blk) {
    const int kb = i0 + 2 + (blk << 6);
    const int vxi = __float_as_int(sx[kb + l]);  // 64 xi's for readlane
    const int done0 = blk << 6;
#pragma unroll
    for (int sub = 0; sub < 4; ++sub) {
      float f[20];
      if (OFF == 0) {
        *(float4*)&f[0]  = sx4[B];
        *(float4*)&f[4]  = sx4[B + 1];
        *(float4*)&f[8]  = sx4[B + 2];
        *(float4*)&f[12] = sx4[B + 3];
      } else {
        *(float4*)&f[0]  = c0;
        *(float4*)&f[4]  = sx4[B + 1];
        *(float4*)&f[8]  = sx4[B + 2];
        *(float4*)&f[12] = sx4[B + 3];
        *(float4*)&f[16] = sx4[B + 4];
        c0 = *(float4*)&f[16];
      }
      B += 4;
#pragma unroll
      for (int u = 0; u < 16; ++u) {
        const int lane = (sub << 4) | u;
        const float xi2 = __int_as_float(__builtin_amdgcn_readlane(vxi, lane));
        push_bool(mask, xi2 - f[OFF + u], RTHR);
      }
      int vv = n - (done0 + (sub << 4));
      vv = vv < 0 ? 0 : (vv > 16 ? 16 : vv);
      const unsigned vm = (0xFFFFu << (16 - vv)) & 0xFFFFu;
      const unsigned q = (mask >> 1) & (mask >> 2) & vm;
      cm2 += __popc(q);
      cm3 += __popc(q & mask);
    }
  }

  // correction: the single out-of-range pair built from real data
  // (start 1022-d uses x[1022],x[1023]); counted iff it fell in this task.
  const int ibad = 1022 - d;
  if (ibad >= i0 && ibad < i0 + n) {
    if (fabsf(sx[ibad] - sx[1022]) <= RTHR &&
        fabsf(sx[ibad + 1] - sx[1023]) <= RTHR)
      cm2 -= 1u;
  }
}

// grid (NB, NSIG), 256 threads = 4 waves.
// Phase 1: in-block normalization, op-order IDENTICAL to prior rounds (absmax
//          has been exactly 0.0 -> do not perturb mean/denom rounding).
// Phase 2: 40 wave-tasks/signal: residue class rr = tid/10 + 1 (d mod 4
//          uniform per wave), group g + 256-wide start-chunk c from tid%10.
//          Lane l: d = 256g + 4l + rr. Sentinel pad (1e30) falsifies all
//          out-of-range booleans; phantom lanes (d > 1021) count 0.
// Phase 3 (fused, NEW): threadfence-reduction. Each block publishes its two
//          partials (agent-scope stores), fences, bumps g_done. The block that
//          sees g_done == 1279 re-arms g_done, acquires, and computes the
//          128 entropies + final MSE itself — final_kernel dispatch removed.
__global__ __launch_bounds__(256) void count_kernel(
    const float* __restrict__ pred, const float* __restrict__ targ,
    unsigned* __restrict__ partial, float* __restrict__ out) {
  const int s = blockIdx.y;
  const int b = blockIdx.x;
  const float* x = (s < 64) ? (pred + s * TLEN) : (targ + (s - 64) * TLEN);
  const int t = threadIdx.x;

  __shared__ __align__(16) float sx[SXPAD];
  __shared__ float red[4];
  __shared__ unsigned redc[8];
  __shared__ int lastf;

  // ---- normalization (bit-identical to prior rounds) ----
  float v[4];
  float sum = 0.f;
#pragma unroll
  for (int k = 0; k < 4; k++) { v[k] = x[t + 256 * k]; sum += v[k]; }
  float wsum = wave_sum_f(sum);
  if ((t & 63) == 0) red[t >> 6] = wsum;
  __syncthreads();
  const float mean = (red[0] + red[1] + red[2] + red[3]) / (float)TLEN;
  __syncthreads();
  float ssq = 0.f;
#pragma unroll
  for (int k = 0; k < 4; k++) { float d0 = v[k] - mean; ssq += d0 * d0; }
  wsum = wave_sum_f(ssq);
  if ((t & 63) == 0) red[t >> 6] = wsum;
  __syncthreads();
  const float var = (red[0] + red[1] + red[2] + red[3]) / (float)(TLEN - 1);
  const float denom = sqrtf(var) + EPSN;
#pragma unroll
  for (int k = 0; k < 4; k++) sx[t + 256 * k] = (v[k] - mean) / denom;
  for (int k = TLEN + t; k < SXPAD; k += 256) sx[k] = 1e30f;  // sentinels
  __syncthreads();

  // ---- task decode (wave-uniform): tid -> (rr, g, c) ----
  const int l = t & 63;
  const int tid = b * 4 + (t >> 6);         // 0..39
  const int rr = tid / 10 + 1;              // residue class 1..4 (d mod 4)
  const int t2 = tid % 10;
  int g, c;
  if (t2 < 4)      { g = 0; c = t2; }
  else if (t2 < 7) { g = 1; c = t2 - 4; }
  else if (t2 < 9) { g = 2; c = t2 - 7; }
  else             { g = 3; c = 0; }
  const int d0  = 256 * g + rr;             // lane-0 diagonal (longest)
  const int len0 = NSAMP - d0;              // lane-0 pair-start count
  const int i0  = 256 * c;
  const int n   = min(256, len0 - i0);      // uniform steps this task
  const int d   = d0 + 4 * l;               // this lane's diagonal

  unsigned cm2 = 0, cm3 = 0;
  const float4* sx4 = (const float4*)sx;
  switch (rr) {  // OFF = (2 + rr) & 3, wave-uniform branch
    case 1: run_task<3>(sx, sx4, i0, n, d, l, cm2, cm3); break;
    case 2: run_task<0>(sx, sx4, i0, n, d, l, cm2, cm3); break;
    case 3: run_task<1>(sx, sx4, i0, n, d, l, cm2, cm3); break;
    default: run_task<2>(sx, sx4, i0, n, d, l, cm2, cm3); break;
  }

  cm2 = wave_sum_u(cm2);
  cm3 = wave_sum_u(cm3);
  if (l == 0) { redc[t >> 6] = cm2; redc[4 + (t >> 6)] = cm3; }
  __syncthreads();

  // ---- publish partials + last-block detection ----
  if (t == 0) {
    const unsigned p0 = redc[0] + redc[1] + redc[2] + redc[3];
    const unsigned p1 = redc[4] + redc[5] + redc[6] + redc[7];
    __hip_atomic_store(&partial[(s * NB + b) * 2], p0,
                       __ATOMIC_RELAXED, __HIP_MEMORY_SCOPE_AGENT);
    __hip_atomic_store(&partial[(s * NB + b) * 2 + 1], p1,
                       __ATOMIC_RELAXED, __HIP_MEMORY_SCOPE_AGENT);
    __threadfence();  // release: partials visible device-wide before the bump
    const unsigned r = __hip_atomic_fetch_add(&g_done, 1u, __ATOMIC_ACQ_REL,
                                              __HIP_MEMORY_SCOPE_AGENT);
    lastf = (r == TOTAL_BLOCKS - 1u) ? 1 : 0;
  }
  __syncthreads();
  if (!lastf) return;

  // ---- last block only: re-arm counter, then fused final reduction ----
  if (t == 0)
    __hip_atomic_store(&g_done, 0u, __ATOMIC_RELAXED, __HIP_MEMORY_SCOPE_AGENT);
  __threadfence();  // acquire: all 1280 blocks' partials are now readable

  float* ents = sx;  // sx is dead; reuse its LDS for the 128 entropies
  if (t < NSIG) {
    unsigned Sp = 0, St = 0;
    for (int c2 = 0; c2 < NB; c2++) {
      Sp += __hip_atomic_load(&partial[(t * NB + c2) * 2],
                              __ATOMIC_RELAXED, __HIP_MEMORY_SCOPE_AGENT);
      St += __hip_atomic_load(&partial[(t * NB + c2) * 2 + 1],
                              __ATOMIC_RELAXED, __HIP_MEMORY_SCOPE_AGENT);
    }
    const unsigned cm  = (unsigned)NSAMP + 2u * Sp;  // self-matches on diagonal
    const unsigned cm1 = (unsigned)NSAMP + 2u * St;
    const float ratio = (float)cm1 / (float)(cm > 0u ? cm : 1u);
    const float e = -logf(fmaxf(ratio, 1e-30f));
    ents[t] = (cm > 0u && cm1 > 0u) ? e : 0.f;
  }
  __syncthreads();
  if (t < 64) {
    const float dd = ents[t] - ents[t + 64];
    const float sq = wave_sum_f(dd * dd);
    if (t == 0) out[0] = sq / 64.f;
  }
}

extern "C" void kernel_launch(void* const* d_in, const int* in_sizes, int n_in,
                              void* d_out, int out_size, void* d_ws, size_t ws_size,
                              hipStream_t stream) {
  const float* pred = (const float*)d_in[0];
  const float* targ = (const float*)d_in[1];
  unsigned* partial = (unsigned*)d_ws;  // NSIG*NB*2 u32 = 10.2 KB

  count_kernel<<<dim3(NB, NSIG), 256, 0, stream>>>(pred, targ, partial,
                                                   (float*)d_out);
}

// Round 2
// 68.243 us; speedup vs baseline: 1.4170x; 1.4170x over previous
//
#include <hip/hip_runtime.h>
#include <math.h>

static constexpr int TLEN  = 1024;  // signal length
static constexpr int NSAMP = 1022;  // N = T - M, M = 2
static constexpr int NSIG  = 128;   // 64 pred + 64 targ
static constexpr int NB    = 10;    // blocks per signal (40 wave-tasks / 4)
static constexpr int SXPAD = 1368;  // sx + sentinel pad (max read idx ~1343)
static constexpr float RTHR = 0.2f;
static constexpr float EPSN = 1e-8f;

// Per-signal match accumulators. Live in module .data (NOT the poisoned
// workspace). Integer atomicAdd is order-independent -> bit-exact totals.
// final_kernel re-arms them to 0 after reading, so every graph replay starts
// clean without an extra memset dispatch. Cross-kernel visibility comes from
// the dispatch boundary (round-1 lesson: per-block __threadfence/device
// counters cost ~20us on multi-XCD gfx950 -- never again).
__device__ unsigned g_cm2[NSIG];
__device__ unsigned g_cm3[NSIG];

__device__ __forceinline__ float wave_sum_f(float v) {
#pragma unroll
  for (int off = 32; off > 0; off >>= 1) v += __shfl_down(v, off);
  return v;
}
__device__ __forceinline__ unsigned wave_sum_u(unsigned v) {
#pragma unroll
  for (int off = 32; off > 0; off >>= 1) v += __shfl_down(v, off);
  return v;
}

// push boolean (|df| <= R) into per-lane 32-bit shift register: mask = 2*mask + b
__device__ __forceinline__ void push_bool(unsigned& mask, float df, float rthr) {
  asm("v_cmp_le_f32 vcc, |%1|, %2\n\t"
      "v_addc_co_u32 %0, vcc, %0, %0, vcc"
      : "+v"(mask)
      : "v"(df), "s"(rthr)
      : "vcc");
}

// One wave-task: lane l owns diagonal d (all lanes share d mod 4 -> OFF is
// wave-uniform and compile-time). Booleans b[k]=|x[k]-x[k+d]|<=R accumulate
// bit-serially (2 VALU); y comes from a rolling 5xfloat4 aligned window:
// exactly one ds_read_b128 per 4 booleans.
// NEW vs round 0: the wave-uniform xi stream (x[i0+2+k]) also comes from a
// rolling float4 window (kb == 2 mod 4 always -> compile-time offset 2) read
// uniformly from LDS (broadcast, conflict-free) -- replaces 16 v_readlane
// VALU issue slots per 16 booleans with 4 LDS-pipe uniform ds_read_b128.
// g[2+u] is the SAME float as the old readlane xi: bit-exact.
template <int OFF>
__device__ __forceinline__ void run_task(const float* sx, const float4* sx4,
                                         int i0, int n, int d, int l,
                                         unsigned& cm2, unsigned& cm3) {
  unsigned mask = 0;
  push_bool(mask, sx[i0] - sx[i0 + d], RTHR);
  push_bool(mask, sx[i0 + 1] - sx[i0 + 1 + d], RTHR);

  int B = (i0 + 2 + d) >> 2;  // per-lane float4 index; 4B + OFF == first y
  float4 c0;
  if (OFF != 0) c0 = sx4[B];  // carried low window reg (y stream)

  int G = i0 >> 2;            // uniform float4 cursor; xi(u) = g[2+u]
  float4 cx = sx4[G];         // carried low window reg (xi stream)

  const int nblk = (n + 63) >> 6;
  for (int blk = 0; blk < nblk; ++blk) {
    const int done0 = blk << 6;
#pragma unroll
    for (int sub = 0; sub < 4; ++sub) {
      float f[20];
      if (OFF == 0) {
        *(float4*)&f[0]  = sx4[B];
        *(float4*)&f[4]  = sx4[B + 1];
        *(float4*)&f[8]  = sx4[B + 2];
        *(float4*)&f[12] = sx4[B + 3];
      } else {
        *(float4*)&f[0]  = c0;
        *(float4*)&f[4]  = sx4[B + 1];
        *(float4*)&f[8]  = sx4[B + 2];
        *(float4*)&f[12] = sx4[B + 3];
        *(float4*)&f[16] = sx4[B + 4];
        c0 = *(float4*)&f[16];
      }
      B += 4;

      float g[20];
      *(float4*)&g[0]  = cx;          // floats 4G .. 4G+3 (xi starts at 4G+2)
      *(float4*)&g[4]  = sx4[G + 1];
      *(float4*)&g[8]  = sx4[G + 2];
      *(float4*)&g[12] = sx4[G + 3];
      *(float4*)&g[16] = sx4[G + 4];
      cx = *(float4*)&g[16];
      G += 4;

#pragma unroll
      for (int u = 0; u < 16; ++u) {
        push_bool(mask, g[2 + u] - f[OFF + u], RTHR);
      }
      int vv = n - (done0 + (sub << 4));
      vv = vv < 0 ? 0 : (vv > 16 ? 16 : vv);
      const unsigned vm = (0xFFFFu << (16 - vv)) & 0xFFFFu;
      const unsigned q = (mask >> 1) & (mask >> 2) & vm;
      cm2 += __popc(q);
      cm3 += __popc(q & mask);
    }
  }

  // correction: the single out-of-range pair built from real data
  // (start 1022-d uses x[1022],x[1023]); counted iff it fell in this task.
  const int ibad = 1022 - d;
  if (ibad >= i0 && ibad < i0 + n) {
    if (fabsf(sx[ibad] - sx[1022]) <= RTHR &&
        fabsf(sx[ibad + 1] - sx[1023]) <= RTHR)
      cm2 -= 1u;
  }
}

// grid (NB, NSIG), 256 threads = 4 waves.
// Phase 1: in-block normalization, op-order IDENTICAL to prior rounds (absmax
//          has been exactly 0.0 -> do not perturb mean/denom rounding).
// Phase 2: 40 wave-tasks/signal: residue class rr = tid/10 + 1 (d mod 4
//          uniform per wave), group g + 256-wide start-chunk c from tid%10.
//          Lane l: d = 256g + 4l + rr. Sentinel pad (1e30) falsifies all
//          out-of-range booleans; phantom lanes (d > 1021) count 0.
// Phase 3: block totals -> 2 low-contention integer atomicAdds into
//          per-signal device globals (10 adds/address, overlapped).
__global__ __launch_bounds__(256) void count_kernel(
    const float* __restrict__ pred, const float* __restrict__ targ) {
  const int s = blockIdx.y;
  const int b = blockIdx.x;
  const float* x = (s < 64) ? (pred + s * TLEN) : (targ + (s - 64) * TLEN);
  const int t = threadIdx.x;

  __shared__ __align__(16) float sx[SXPAD];
  __shared__ float red[4];
  __shared__ unsigned redc[8];

  // ---- normalization (bit-identical to prior rounds) ----
  float v[4];
  float sum = 0.f;
#pragma unroll
  for (int k = 0; k < 4; k++) { v[k] = x[t + 256 * k]; sum += v[k]; }
  float wsum = wave_sum_f(sum);
  if ((t & 63) == 0) red[t >> 6] = wsum;
  __syncthreads();
  const float mean = (red[0] + red[1] + red[2] + red[3]) / (float)TLEN;
  __syncthreads();
  float ssq = 0.f;
#pragma unroll
  for (int k = 0; k < 4; k++) { float d0 = v[k] - mean; ssq += d0 * d0; }
  wsum = wave_sum_f(ssq);
  if ((t & 63) == 0) red[t >> 6] = wsum;
  __syncthreads();
  const float var = (red[0] + red[1] + red[2] + red[3]) / (float)(TLEN - 1);
  const float denom = sqrtf(var) + EPSN;
#pragma unroll
  for (int k = 0; k < 4; k++) sx[t + 256 * k] = (v[k] - mean) / denom;
  for (int k = TLEN + t; k < SXPAD; k += 256) sx[k] = 1e30f;  // sentinels
  __syncthreads();

  // ---- task decode (wave-uniform): tid -> (rr, g, c) ----
  const int l = t & 63;
  const int tid = b * 4 + (t >> 6);         // 0..39
  const int rr = tid / 10 + 1;              // residue class 1..4 (d mod 4)
  const int t2 = tid % 10;
  int g, c;
  if (t2 < 4)      { g = 0; c = t2; }
  else if (t2 < 7) { g = 1; c = t2 - 4; }
  else if (t2 < 9) { g = 2; c = t2 - 7; }
  else             { g = 3; c = 0; }
  const int d0  = 256 * g + rr;             // lane-0 diagonal (longest)
  const int len0 = NSAMP - d0;              // lane-0 pair-start count
  const int i0  = 256 * c;
  const int n   = min(256, len0 - i0);      // uniform steps this task
  const int d   = d0 + 4 * l;               // this lane's diagonal

  unsigned cm2 = 0, cm3 = 0;
  const float4* sx4 = (const float4*)sx;
  switch (rr) {  // OFF = (2 + rr) & 3, wave-uniform branch
    case 1: run_task<3>(sx, sx4, i0, n, d, l, cm2, cm3); break;
    case 2: run_task<0>(sx, sx4, i0, n, d, l, cm2, cm3); break;
    case 3: run_task<1>(sx, sx4, i0, n, d, l, cm2, cm3); break;
    default: run_task<2>(sx, sx4, i0, n, d, l, cm2, cm3); break;
  }

  cm2 = wave_sum_u(cm2);
  cm3 = wave_sum_u(cm3);
  if (l == 0) { redc[t >> 6] = cm2; redc[4 + (t >> 6)] = cm3; }
  __syncthreads();
  if (t == 0) {
    atomicAdd(&g_cm2[s], redc[0] + redc[1] + redc[2] + redc[3]);
    atomicAdd(&g_cm3[s], redc[4] + redc[5] + redc[6] + redc[7]);
  }
}

// 128 threads: thread s -> signal s entropy; then MSE over the 64 channels.
// Reads the device-global accumulators (visible via the dispatch boundary)
// and re-arms them to 0 for the next graph replay.
__global__ __launch_bounds__(128) void final_kernel(float* __restrict__ out) {
  __shared__ float ents[128];
  const int s = threadIdx.x;
  const unsigned Sp = __hip_atomic_load(&g_cm2[s], __ATOMIC_RELAXED,
                                        __HIP_MEMORY_SCOPE_AGENT);
  const unsigned St = __hip_atomic_load(&g_cm3[s], __ATOMIC_RELAXED,
                                        __HIP_MEMORY_SCOPE_AGENT);
  __hip_atomic_store(&g_cm2[s], 0u, __ATOMIC_RELAXED, __HIP_MEMORY_SCOPE_AGENT);
  __hip_atomic_store(&g_cm3[s], 0u, __ATOMIC_RELAXED, __HIP_MEMORY_SCOPE_AGENT);
  const unsigned cm  = (unsigned)NSAMP + 2u * Sp;  // self-matches on diagonal
  const unsigned cm1 = (unsigned)NSAMP + 2u * St;
  const float ratio = (float)cm1 / (float)(cm > 0u ? cm : 1u);
  const float e = -logf(fmaxf(ratio, 1e-30f));
  ents[s] = (cm > 0u && cm1 > 0u) ? e : 0.f;
  __syncthreads();
  if (s < 64) {
    const float dd = ents[s] - ents[s + 64];
    const float sq = wave_sum_f(dd * dd);
    if (s == 0) out[0] = sq / 64.f;
  }
}

extern "C" void kernel_launch(void* const* d_in, const int* in_sizes, int n_in,
                              void* d_out, int out_size, void* d_ws, size_t ws_size,
                              hipStream_t stream) {
  const float* pred = (const float*)d_in[0];
  const float* targ = (const float*)d_in[1];
  (void)d_ws; (void)ws_size;  // workspace unused (it is re-poisoned anyway)

  count_kernel<<<dim3(NB, NSIG), 256, 0, stream>>>(pred, targ);
  final_kernel<<<1, 128, 0, stream>>>((float*)d_out);
}